// Round 17
// baseline (507.745 us; speedup 1.0000x reference)
//
#include <hip/hip_runtime.h>
#include <hip/hip_bf16.h>

#define NROWS 131072
#define DIN   768
#define DD    512
#define KK    256

#define BM    64
#define BK    32
#define NSTEP 24            // DIN/BK
#define MARGIN_TH 1e-3f

typedef __attribute__((ext_vector_type(8))) short  short8;
typedef __attribute__((ext_vector_type(8))) unsigned short ushort8;
typedef __attribute__((ext_vector_type(4))) float  f32x4;

__device__ __forceinline__ unsigned short f2bf_rn(float x) {
    unsigned int u = __float_as_uint(x);
    unsigned int r = (u + 0x7fffu + ((u >> 16) & 1u)) >> 16;   // RNE
    return (unsigned short)r;
}
__device__ __forceinline__ float bf2f(unsigned short h) {
    return __uint_as_float(((unsigned int)h) << 16);
}

// hi = RNE bf16 of x; lo = truncated bf16 of (x - hi) -- error ~2^-18 relative.
__device__ __forceinline__ void cvt_store(f32x4 a, f32x4 b,
                                          unsigned short* hd, unsigned short* ldst) {
    ushort8 hv, lv;
#pragma unroll
    for (int j = 0; j < 4; ++j) {
        unsigned short h = f2bf_rn(a[j]);
        hv[j] = h; lv[j] = (unsigned short)(__float_as_uint(a[j] - bf2f(h)) >> 16);
    }
#pragma unroll
    for (int j = 0; j < 4; ++j) {
        unsigned short h = f2bf_rn(b[j]);
        hv[j + 4] = h; lv[j + 4] = (unsigned short)(__float_as_uint(b[j] - bf2f(h)) >> 16);
    }
    *(ushort8*)hd = hv;
    *(ushort8*)ldst = lv;
}

// ---------------- pre: w2 GEMM (0..47) + c2 (48) + maps GEMMs (49..96) ------------------
// w2: Wp bf16 hi+lo in bulk tile order: Wp[((din>>5)*2048+((din>>3)&3)*256+col)*8+(din&7)],
//     lo at +8192 elems per 32-k step.
// maps: 3 layers x 16 row-chunks of 16; fp32 tiled GEMM scores + in-GEMM cand norms;
//     fp32 top-2, fp64 in-block recheck when gap < 1e-3 (expected 0 rows).
__global__ __launch_bounds__(256) void pre_kernel(const float* __restrict__ enc_w,
                                                  const float* __restrict__ enc_b,
                                                  const float* __restrict__ cb,
                                                  unsigned short* __restrict__ Wp,
                                                  float* __restrict__ c2,
                                                  int* __restrict__ maps,
                                                  int* __restrict__ counters) {
    const int t = threadIdx.x;
    const int lane = t & 63, wv = t >> 6;

    if (blockIdx.x < 48) {
        // ================= w2 GEMM role =================
        __shared__ float As[64][21];
        __shared__ float Bs[64][21];
        const int din0 = (blockIdx.x >> 2) * 64;
        const int col0 = (blockIdx.x & 3) * 64;
        const int tr = t >> 4, tc = t & 15;
        const int lr_ = t >> 2, k4 = (t & 3) * 4;

        float acc[4][4];
#pragma unroll
        for (int i = 0; i < 4; ++i)
#pragma unroll
            for (int j = 0; j < 4; ++j) acc[i][j] = 0.f;

        for (int k0 = 0; k0 < DD; k0 += 16) {
            {
                const float* ap = enc_w + (size_t)(din0 + lr_) * DD + k0 + k4;
                const float* bp = cb + (size_t)(col0 + lr_) * DD + k0 + k4;
                f32x4 av = *(const f32x4*)ap;
                f32x4 bv = *(const f32x4*)bp;
                *(f32x4*)&As[lr_][k4] = av;
                *(f32x4*)&Bs[lr_][k4] = bv;
            }
            __syncthreads();
#pragma unroll
            for (int kk = 0; kk < 16; ++kk) {
                float a[4], b[4];
#pragma unroll
                for (int i = 0; i < 4; ++i) a[i] = As[tr * 4 + i][kk];
#pragma unroll
                for (int j = 0; j < 4; ++j) b[j] = Bs[tc * 4 + j][kk];
#pragma unroll
                for (int i = 0; i < 4; ++i)
#pragma unroll
                    for (int j = 0; j < 4; ++j) acc[i][j] = fmaf(a[i], b[j], acc[i][j]);
            }
            __syncthreads();
        }
#pragma unroll
        for (int i = 0; i < 4; ++i) {
            int din = din0 + tr * 4 + i;
            size_t ub = (size_t)(din >> 5) * 2048 + (size_t)((din >> 3) & 3) * 256;
            int jj = din & 7;
#pragma unroll
            for (int j = 0; j < 4; ++j) {
                int col = col0 + tc * 4 + j;
                float w = -2.0f * acc[i][j];
                unsigned short h = f2bf_rn(w);
                unsigned short l = (unsigned short)(__float_as_uint(w - bf2f(h)) >> 16);
                size_t p = (ub + col) * 8 + jj;
                Wp[p] = h;
                Wp[p + 8192] = l;
            }
        }
    } else if (blockIdx.x == 48) {
        // ================= c2 role (fp64 compute, fp32 store) =================
        __shared__ float bb[DD];
        for (int d = t; d < DD; d += 256) bb[d] = enc_b[d];
        __syncthreads();
        for (int c4 = 0; c4 < 16; ++c4) {
            int col0 = wv * 64 + c4 * 4;
            const float* C0 = cb + (size_t)col0 * DD;
            const float* C1 = C0 + DD;
            const float* C2 = C0 + 2 * DD;
            const float* C3 = C0 + 3 * DD;
            double b0 = 0, b1 = 0, b2 = 0, b3 = 0, n0 = 0, n1 = 0, n2 = 0, n3 = 0;
#pragma unroll
            for (int i = 0; i < 8; ++i) {
                int d = lane + 64 * i;
                double b = bb[d];
                double c0v = C0[d], c1v = C1[d], c2v = C2[d], c3v = C3[d];
                b0 += b * c0v; n0 += c0v * c0v;
                b1 += b * c1v; n1 += c1v * c1v;
                b2 += b * c2v; n2 += c2v * c2v;
                b3 += b * c3v; n3 += c3v * c3v;
            }
#pragma unroll
            for (int off = 1; off < 64; off <<= 1) {
                b0 += __shfl_xor(b0, off); n0 += __shfl_xor(n0, off);
                b1 += __shfl_xor(b1, off); n1 += __shfl_xor(n1, off);
                b2 += __shfl_xor(b2, off); n2 += __shfl_xor(n2, off);
                b3 += __shfl_xor(b3, off); n3 += __shfl_xor(n3, off);
            }
            if (lane == 0) {
                c2[col0]     = (float)(-2.0 * b0 + n0);
                c2[col0 + 1] = (float)(-2.0 * b1 + n1);
                c2[col0 + 2] = (float)(-2.0 * b2 + n2);
                c2[col0 + 3] = (float)(-2.0 * b3 + n3);
            }
        }
        if (t == 0) counters[0] = 0;
    } else {
        // ================= maps role =================
        int b = blockIdx.x - 49;       // 0..47
        int lidx = b >> 4;             // layer 0..2 (maps cb_l -> cb_{l+1})
        int rc   = b & 15;             // row chunk of 16
        const float* A = cb + (size_t)lidx * KK * DD + (size_t)rc * 16 * DD;
        const float* B = cb + (size_t)(lidx + 1) * KK * DD;

        __shared__ float As2[16][21];
        __shared__ float Bs2[64][21];
        __shared__ float nrm64[64];
        __shared__ float Rv[16][16];
        __shared__ float Rs[16][16];
        __shared__ int   Rc[16][16];
        __shared__ int   flags[16];
        __shared__ int   nflag;
        __shared__ double sv[256];
        __shared__ int    si[256];

        const int tr = t >> 4, tc = t & 15;
        float v1 = 3.4e38f, v2 = 3.4e38f; int c1 = 1 << 20;

        for (int cc = 0; cc < 4; ++cc) {
            float acc[4] = {0.f, 0.f, 0.f, 0.f};
            float nacc[4] = {0.f, 0.f, 0.f, 0.f};
            for (int k0 = 0; k0 < DD; k0 += 16) {
                if (t < 64) {
                    const float* ap = A + (size_t)(t >> 2) * DD + k0 + (t & 3) * 4;
                    *(f32x4*)&As2[t >> 2][(t & 3) * 4] = *(const f32x4*)ap;
                }
                {
                    const float* bp = B + (size_t)(cc * 64 + (t >> 2)) * DD + k0 + (t & 3) * 4;
                    *(f32x4*)&Bs2[t >> 2][(t & 3) * 4] = *(const f32x4*)bp;
                }
                __syncthreads();
#pragma unroll
                for (int kk = 0; kk < 16; ++kk) {
                    float a = As2[tr][kk];
                    float bq[4];
#pragma unroll
                    for (int j = 0; j < 4; ++j) bq[j] = Bs2[tc * 4 + j][kk];
#pragma unroll
                    for (int j = 0; j < 4; ++j) acc[j] = fmaf(a, bq[j], acc[j]);
                    if (tr == 0) {
#pragma unroll
                        for (int j = 0; j < 4; ++j) nacc[j] = fmaf(bq[j], bq[j], nacc[j]);
                    }
                }
                __syncthreads();
            }
            if (tr == 0) {
#pragma unroll
                for (int j = 0; j < 4; ++j) nrm64[tc * 4 + j] = nacc[j];
            }
            __syncthreads();
#pragma unroll
            for (int j = 0; j < 4; ++j) {
                float s = -2.0f * acc[j] + nrm64[tc * 4 + j];
                if (s < v1) { v2 = v1; v1 = s; c1 = cc * 64 + tc * 4 + j; }
                else if (s < v2) v2 = s;
            }
            __syncthreads();
        }
        Rv[tr][tc] = v1; Rc[tr][tc] = c1; Rs[tr][tc] = v2;
        if (t == 0) nflag = 0;
        __syncthreads();
        if (t < 16) {
            float bv1 = 3.4e38f, bv2 = 3.4e38f; int bc = 1 << 20;
            for (int q = 0; q < 16; ++q) {
                float av = Rv[t][q], as = Rs[t][q]; int ac = Rc[t][q];
                if (av < bv1 || (av == bv1 && ac < bc)) { bv2 = fminf(bv1, as); bv1 = av; bc = ac; }
                else bv2 = fminf(bv2, av);
            }
            maps[lidx * KK + rc * 16 + t] = bc;
            if (bv2 - bv1 < 1e-3f) { int p = atomicAdd(&nflag, 1); flags[p] = t; }
        }
        __syncthreads();
        int nf = nflag;
        for (int f = 0; f < nf; ++f) {
            int r = flags[f];
            const float* Ar = A + (size_t)r * DD;
            const float* Bj = B + (size_t)t * DD;
            double dot = 0.0, nn = 0.0;
            for (int d = 0; d < DD; ++d) { double cv = Bj[d]; dot += (double)Ar[d] * cv; nn += cv * cv; }
            sv[t] = -2.0 * dot + nn; si[t] = t;
            __syncthreads();
            for (int off = 128; off; off >>= 1) {
                if (t < off) {
                    double a = sv[t], bq = sv[t + off];
                    if (bq < a || (bq == a && si[t + off] < si[t])) { sv[t] = bq; si[t] = si[t + off]; }
                }
                __syncthreads();
            }
            if (t == 0) maps[lidx * KK + rc * 16 + r] = si[0];
            __syncthreads();
        }
    }
}

// ---------------- tdec: Tdec[k] = (sum of 4 chained codebook rows) @ dec_w + dec_b -------
// grid 64 blocks x 4 k each; fp32 (error ~1e-5 << 9.1e-3 output tolerance).
__global__ __launch_bounds__(256) void tdec_kernel(const float* __restrict__ cb,
                                                   const float* __restrict__ dec_w,
                                                   const float* __restrict__ dec_b,
                                                   const int* __restrict__ maps,
                                                   float* __restrict__ Tdec) {
    const int k0 = blockIdx.x * 4;
    const int t = threadIdx.x;
    __shared__ float Ts[4][DD];
#pragma unroll
    for (int r = 0; r < 4; ++r) {
        int i1 = k0 + r;
        int i2 = maps[0 * KK + i1];
        int i3 = maps[1 * KK + i2];
        int i4 = maps[2 * KK + i3];
        for (int d = t; d < DD; d += 256)
            Ts[r][d] = cb[(size_t)i1 * DD + d]
                     + cb[(size_t)KK * DD + (size_t)i2 * DD + d]
                     + cb[(size_t)2 * KK * DD + (size_t)i3 * DD + d]
                     + cb[(size_t)3 * KK * DD + (size_t)i4 * DD + d];
    }
    __syncthreads();
#pragma unroll
    for (int half = 0; half < 2; ++half) {
        int n = t + half * 256;
        float a0 = 0.f, a1 = 0.f, a2 = 0.f, a3 = 0.f;
        for (int d = 0; d < DD; ++d) {
            float w = dec_w[(size_t)d * DD + n];
            a0 = fmaf(Ts[0][d], w, a0);
            a1 = fmaf(Ts[1][d], w, a1);
            a2 = fmaf(Ts[2][d], w, a2);
            a3 = fmaf(Ts[3][d], w, a3);
        }
        float bsv = dec_b[n];
        Tdec[(size_t)(k0 + 0) * DD + n] = a0 + bsv;
        Tdec[(size_t)(k0 + 1) * DD + n] = a1 + bsv;
        Tdec[(size_t)(k0 + 2) * DD + n] = a2 + bsv;
        Tdec[(size_t)(k0 + 3) * DD + n] = a3 + bsv;
    }
}

// ---------------- bulk: 3-term bf16 MFMA (round-9 verbatim: best measured 237 us) --------
__global__ __launch_bounds__(256, 2) void bulk_kernel(const float* __restrict__ X,
                                                      const unsigned short* __restrict__ Wp,
                                                      const float* __restrict__ c2,
                                                      const float* __restrict__ Tdec,
                                                      float* __restrict__ out,
                                                      int* __restrict__ counters,
                                                      int* __restrict__ list1) {
    __shared__ __align__(16) unsigned short Xh[2][2048];   // 2 x 4KB
    __shared__ __align__(16) unsigned short Xl[2][2048];   // 2 x 4KB
    __shared__ float Rv1[BM * 4];
    __shared__ float Rv2[BM * 4];
    __shared__ int   Ri1[BM * 4];
    __shared__ int   rowIdx[BM];

    const int t    = threadIdx.x;
    const int lane = t & 63;
    const int wv   = t >> 6;        // col-group 0..3
    const int lr   = lane & 15;
    const int lg   = lane >> 4;
    const int row0 = blockIdx.x * BM;

    f32x4 acc[4][4];
#pragma unroll
    for (int rf = 0; rf < 4; ++rf)
#pragma unroll
        for (int cf = 0; cf < 4; ++cf) acc[rf][cf] = (f32x4){0.f, 0.f, 0.f, 0.f};

    const int xrow = t >> 2, xsub = t & 3;
    const float* xp_base = X + (size_t)(row0 + xrow) * DIN + xsub * 8;
    const int xu = (xsub * 64 + xrow) ^ (xsub << 1);

    const unsigned short* wlane = Wp + (size_t)(lg * 256 + wv * 64 + lr) * 8;

    f32x4 nxa, nxb;
    short8 wh[2][4], wl[4];

    // ---- prologue ----
    {
        f32x4 a = __builtin_nontemporal_load((const f32x4*)xp_base);
        f32x4 b = __builtin_nontemporal_load((const f32x4*)(xp_base + 4));
        cvt_store(a, b, &Xh[0][xu * 8], &Xl[0][xu * 8]);
        nxa = __builtin_nontemporal_load((const f32x4*)(xp_base + BK));
        nxb = __builtin_nontemporal_load((const f32x4*)(xp_base + BK + 4));
#pragma unroll
        for (int cf = 0; cf < 4; ++cf)
            wh[0][cf] = *(const short8*)(wlane + cf * 128);
    }
    __syncthreads();

#define HALF(P, S)                                                                          \
    {                                                                                       \
        const int s_ = (S);                                                                 \
        short8 ah[4], al[4];                                                                \
        _Pragma("unroll")                                                                   \
        for (int rf = 0; rf < 4; ++rf) {                                                    \
            int u = (lg * 64 + rf * 16 + lr) ^ (lg << 1);                                   \
            ah[rf] = *(const short8*)&Xh[P][u * 8];                                         \
            al[rf] = *(const short8*)&Xl[P][u * 8];                                         \
        }                                                                                   \
        {                                                                                   \
            const unsigned short* wsl = wlane + (size_t)s_ * 16384 + 8192;                  \
            _Pragma("unroll")                                                               \
            for (int cf = 0; cf < 4; ++cf)                                                  \
                wl[cf] = *(const short8*)(wsl + cf * 128);                                  \
        }                                                                                   \
        if (s_ + 1 < NSTEP)                                                                 \
            cvt_store(nxa, nxb, &Xh[(P) ^ 1][xu * 8], &Xl[(P) ^ 1][xu * 8]);                \
        if (s_ + 2 < NSTEP) {                                                               \
            nxa = __builtin_nontemporal_load((const f32x4*)(xp_base + (s_ + 2) * BK));      \
            nxb = __builtin_nontemporal_load((const f32x4*)(xp_base + (s_ + 2) * BK + 4));  \
        }                                                                                   \
        if (s_ + 1 < NSTEP) {                                                               \
            const unsigned short* wsh = wlane + (size_t)(s_ + 1) * 16384;                   \
            _Pragma("unroll")                                                               \
            for (int cf = 0; cf < 4; ++cf)                                                  \
                wh[(P) ^ 1][cf] = *(const short8*)(wsh + cf * 128);                         \
        }                                                                                   \
        asm volatile("s_waitcnt lgkmcnt(0)" ::: "memory");                                  \
        __builtin_amdgcn_sched_barrier(0);                                                  \
        __builtin_amdgcn_s_setprio(1);                                                      \
        _Pragma("unroll")                                                                   \
        for (int cf = 0; cf < 4; ++cf) {                                                    \
            _Pragma("unroll")                                                               \
            for (int rf = 0; rf < 4; ++rf) {                                                \
                acc[rf][cf] = __builtin_amdgcn_mfma_f32_16x16x32_bf16(al[rf], wh[P][cf], acc[rf][cf], 0, 0, 0); \
                acc[rf][cf] = __builtin_amdgcn_mfma_f32_16x16x32_bf16(ah[rf], wh[P][cf], acc[rf][cf], 0, 0, 0); \
            }                                                                               \
        }                                                                                   \
        _Pragma("unroll")                                                                   \
        for (int cf = 0; cf < 4; ++cf) {                                                    \
            _Pragma("unroll")                                                               \
            for (int rf = 0; rf < 4; ++rf) {                                                \
                acc[rf][cf] = __builtin_amdgcn_mfma_f32_16x16x32_bf16(ah[rf], wl[cf], acc[rf][cf], 0, 0, 0); \
            }                                                                               \
        }                                                                                   \
        __builtin_amdgcn_s_setprio(0);                                                      \
        __builtin_amdgcn_s_barrier();                                                       \
    }

#pragma unroll 1
    for (int s2 = 0; s2 < NSTEP / 2; ++s2) {
        HALF(0, 2 * s2);
        HALF(1, 2 * s2 + 1);
    }
#undef HALF

    __syncthreads();   // full drain before epilogue

    float c2v[4];
#pragma unroll
    for (int cf = 0; cf < 4; ++cf) c2v[cf] = c2[wv * 64 + cf * 16 + lr];

#pragma unroll
    for (int rf = 0; rf < 4; ++rf) {
#pragma unroll
        for (int reg = 0; reg < 4; ++reg) {
            float v1 = 3.4e38f, v2 = 3.4e38f;
            int   c1 = 1 << 20;
#pragma unroll
            for (int cf = 0; cf < 4; ++cf) {
                float sc = acc[rf][cf][reg] + c2v[cf];
                int col = wv * 64 + cf * 16 + lr;
                if (sc < v1 || (sc == v1 && col < c1)) { v2 = v1; v1 = sc; c1 = col; }
                else if (sc < v2) v2 = sc;
            }
#pragma unroll
            for (int off = 1; off < 16; off <<= 1) {
                float ov1 = __shfl_xor(v1, off);
                float ov2 = __shfl_xor(v2, off);
                int   oc1 = __shfl_xor(c1, off);
                if (ov1 < v1 || (ov1 == v1 && oc1 < c1)) { v2 = fminf(v1, ov2); v1 = ov1; c1 = oc1; }
                else v2 = fminf(v2, ov1);
            }
            if (lr == 0) {
                int r = rf * 16 + lg * 4 + reg;
                Rv1[r * 4 + wv] = v1; Ri1[r * 4 + wv] = c1; Rv2[r * 4 + wv] = v2;
            }
        }
    }
    __syncthreads();

    if (t < BM) {
        float v1 = Rv1[t * 4], v2 = Rv2[t * 4];
        int   c1 = Ri1[t * 4];
#pragma unroll
        for (int g = 1; g < 4; ++g) {
            float bv = Rv1[t * 4 + g], bs = Rv2[t * 4 + g];
            int   bc = Ri1[t * 4 + g];
            if (bv < v1) { v2 = fminf(v1, bs); v1 = bv; c1 = bc; }
            else         { v2 = fminf(v2, bv); }
        }
        rowIdx[t] = c1;
        if (v2 - v1 < MARGIN_TH) {
            int pos = atomicAdd(&counters[0], 1);
            list1[pos] = row0 + t;
        }
    }
    __syncthreads();

#pragma unroll
    for (int m = 0; m < 32; ++m) {
        int lin = m * 256 + t;
        int r   = lin >> 7;
        int c4  = (lin & 127) * 4;
        f32x4 v = *(const f32x4*)(Tdec + (size_t)rowIdx[r] * DD + c4);
        __builtin_nontemporal_store(v, (f32x4*)(out + (size_t)(row0 + r) * DD + c4));
    }
}

// ---------------- refine: fp64-exact re-decision for near-tie rows (round-9 verbatim) ----
__global__ __launch_bounds__(256) void refine_kernel(const float* __restrict__ X,
                                                     const float* __restrict__ enc_w,
                                                     const float* __restrict__ enc_b,
                                                     const float* __restrict__ cb,
                                                     const float* __restrict__ Tdec,
                                                     float* __restrict__ out,
                                                     const int* __restrict__ counters,
                                                     const int* __restrict__ list1) {
    int cnt = counters[0];
    __shared__ double r0[DD];
    __shared__ double sv[256];
    __shared__ int    si[256];
    for (int it = blockIdx.x; it < cnt; it += gridDim.x) {
        int n = list1[it];
        const float* xr = X + (size_t)n * DIN;
        for (int d = threadIdx.x; d < DD; d += 256) {
            double a0 = 0, a1 = 0, a2 = 0, a3 = 0;
            for (int j = 0; j < DIN; j += 4) {
                a0 += (double)xr[j]     * (double)enc_w[(size_t)(j)     * DD + d];
                a1 += (double)xr[j + 1] * (double)enc_w[(size_t)(j + 1) * DD + d];
                a2 += (double)xr[j + 2] * (double)enc_w[(size_t)(j + 2) * DD + d];
                a3 += (double)xr[j + 3] * (double)enc_w[(size_t)(j + 3) * DD + d];
            }
            r0[d] = (double)enc_b[d] + a0 + a1 + a2 + a3;
        }
        __syncthreads();
        int k = threadIdx.x;
        const float* ck = cb + (size_t)k * DD;
        double d0 = 0, d1 = 0, n0 = 0, n1 = 0;
        for (int d = 0; d < DD; d += 2) {
            double c0 = ck[d], c1 = ck[d + 1];
            d0 += r0[d] * c0;     n0 += c0 * c0;
            d1 += r0[d + 1] * c1; n1 += c1 * c1;
        }
        sv[k] = -2.0 * (d0 + d1) + (n0 + n1); si[k] = k;
        __syncthreads();
        for (int off = 128; off; off >>= 1) {
            if (k < off) {
                double a = sv[k], b = sv[k + off];
                if (b < a || (b == a && si[k + off] < si[k])) { sv[k] = b; si[k] = si[k + off]; }
            }
            __syncthreads();
        }
        int best = si[0];
        for (int c = threadIdx.x; c < DD; c += 256)
            out[(size_t)n * DD + c] = Tdec[(size_t)best * DD + c];
        __syncthreads();
    }
}

extern "C" void kernel_launch(void* const* d_in, const int* in_sizes, int n_in,
                              void* d_out, int out_size, void* d_ws, size_t ws_size,
                              hipStream_t stream) {
    const float* X     = (const float*)d_in[0];
    const float* enc_w = (const float*)d_in[1];
    const float* enc_b = (const float*)d_in[2];
    const float* cb    = (const float*)d_in[3];
    const float* dec_w = (const float*)d_in[4];
    const float* dec_b = (const float*)d_in[5];
    float* out = (float*)d_out;

    char* ws = (char*)d_ws;
    unsigned short* Wp  = (unsigned short*)(ws + 0);         // 24*2048*8*2B = 786432
    float*  c2      = (float*) (ws + 786432);                // 1024
    float*  Tdec    = (float*) (ws + 787456);                // 524288
    int*    maps    = (int*)   (ws + 1311744);               // 3072
    int*    counters= (int*)   (ws + 1314816);               // 1 int (+pad)
    int*    list1   = (int*)   (ws + 1314848);               // near-tie rows

    hipLaunchKernelGGL(pre_kernel,    dim3(97),         dim3(256), 0, stream,
                       enc_w, enc_b, cb, Wp, c2, maps, counters);
    hipLaunchKernelGGL(tdec_kernel,   dim3(64),         dim3(256), 0, stream,
                       cb, dec_w, dec_b, maps, Tdec);
    hipLaunchKernelGGL(bulk_kernel,   dim3(NROWS / BM), dim3(256), 0, stream,
                       X, Wp, c2, Tdec, out, counters, list1);
    hipLaunchKernelGGL(refine_kernel, dim3(1024),       dim3(256), 0, stream,
                       X, enc_w, enc_b, cb, Tdec, out, counters, list1);
}